// Round 1
// baseline (228.175 us; speedup 1.0000x reference)
//
#include <hip/hip_runtime.h>
#include <math.h>

// WHT_expansion: rows of 256 f32 -> pad to 512 -> WHT -> pointwise -> WHT -> 512 f32.
// One row per wave64. Lane l holds j = 4l+c (c=0..3) and j = 256+4l+c.
// Bits 0-1 of j: register butterflies. Bits 2-7: __shfl_xor butterflies.
// Bit 8: register pair (i, i+4). First transform uses H512[x;0] = [H256 x; H256 x].

__global__ __launch_bounds__(256) void wht512_kernel(
    const float* __restrict__ x, const float* __restrict__ T,
    float* __restrict__ y, int nrows)
{
    const int lane = threadIdx.x & 63;
    const int wib  = threadIdx.x >> 6;
    const int wpb  = blockDim.x >> 6;
    const int wave   = blockIdx.x * wpb + wib;
    const int nwaves = gridDim.x * wpb;

    // |T| fragments for this lane's 8 elements (loop-invariant)
    float4 t0 = *reinterpret_cast<const float4*>(T + 4 * lane);
    float4 t1 = *reinterpret_cast<const float4*>(T + 256 + 4 * lane);
    const float Ta0 = fabsf(t0.x), Ta1 = fabsf(t0.y), Ta2 = fabsf(t0.z), Ta3 = fabsf(t0.w);
    const float Ta4 = fabsf(t1.x), Ta5 = fabsf(t1.y), Ta6 = fabsf(t1.z), Ta7 = fabsf(t1.w);

    // butterfly signs per cross-lane stage (loop-invariant): +1 if lane bit clear
    float sg[6];
#pragma unroll
    for (int k = 0; k < 6; ++k) sg[k] = (lane & (1 << k)) ? -1.0f : 1.0f;

    const float S = 0.044194173824159216f; // 2^-4.5 = 1/sqrt(512)

    for (int row = wave; row < nrows; row += nwaves) {
        const size_t ibase = (size_t)row * 256 + 4 * lane;
        float4 xa = *reinterpret_cast<const float4*>(x + ibase);
        float v0 = xa.x, v1 = xa.y, v2 = xa.z, v3 = xa.w;

        // ---- WHT-256 on v0..v3 (j = 4l + c) ----
        // register stages: bit 0 then bit 1
        {
            float a, b;
            a = v0; b = v1; v0 = a + b; v1 = a - b;
            a = v2; b = v3; v2 = a + b; v3 = a - b;
            a = v0; b = v2; v0 = a + b; v2 = a - b;
            a = v1; b = v3; v1 = a + b; v3 = a - b;
        }
        // cross-lane stages: j bits 2..7 = lane bits 0..5
#pragma unroll
        for (int k = 0; k < 6; ++k) {
            const int m = 1 << k;
            float p0 = __shfl_xor(v0, m);
            float p1 = __shfl_xor(v1, m);
            float p2 = __shfl_xor(v2, m);
            float p3 = __shfl_xor(v3, m);
            v0 = fmaf(sg[k], v0, p0);
            v1 = fmaf(sg[k], v1, p1);
            v2 = fmaf(sg[k], v2, p2);
            v3 = fmaf(sg[k], v3, p3);
        }

        // f1 = S*h duplicated into both halves; then pointwise nonlinearity
        const float u0 = S * v0, u1 = S * v1, u2 = S * v2, u3 = S * v3;

        float w0, w1, w2, w3, w4, w5, w6, w7;
        {
            float r;
            r = fmaxf(fabsf(u0) - Ta0, 0.0f); w0 = tanhf(u0) * r;
            r = fmaxf(fabsf(u1) - Ta1, 0.0f); w1 = tanhf(u1) * r;
            r = fmaxf(fabsf(u2) - Ta2, 0.0f); w2 = tanhf(u2) * r;
            r = fmaxf(fabsf(u3) - Ta3, 0.0f); w3 = tanhf(u3) * r;
            r = fmaxf(fabsf(u0) - Ta4, 0.0f); w4 = tanhf(u0) * r;
            r = fmaxf(fabsf(u1) - Ta5, 0.0f); w5 = tanhf(u1) * r;
            r = fmaxf(fabsf(u2) - Ta6, 0.0f); w6 = tanhf(u2) * r;
            r = fmaxf(fabsf(u3) - Ta7, 0.0f); w7 = tanhf(u3) * r;
        }
        // f3[0] = f1[0]  (global element j==0 lives in lane 0, c=0)
        w0 = (lane == 0) ? u0 : w0;

        // ---- WHT-512 on w0..w7 ----
        // register stages: bit 0, bit 1
        {
            float a, b;
            a = w0; b = w1; w0 = a + b; w1 = a - b;
            a = w2; b = w3; w2 = a + b; w3 = a - b;
            a = w4; b = w5; w4 = a + b; w5 = a - b;
            a = w6; b = w7; w6 = a + b; w7 = a - b;
            a = w0; b = w2; w0 = a + b; w2 = a - b;
            a = w1; b = w3; w1 = a + b; w3 = a - b;
            a = w4; b = w6; w4 = a + b; w6 = a - b;
            a = w5; b = w7; w5 = a + b; w7 = a - b;
        }
        // cross-lane stages: j bits 2..7
#pragma unroll
        for (int k = 0; k < 6; ++k) {
            const int m = 1 << k;
            float p0 = __shfl_xor(w0, m);
            float p1 = __shfl_xor(w1, m);
            float p2 = __shfl_xor(w2, m);
            float p3 = __shfl_xor(w3, m);
            float p4 = __shfl_xor(w4, m);
            float p5 = __shfl_xor(w5, m);
            float p6 = __shfl_xor(w6, m);
            float p7 = __shfl_xor(w7, m);
            w0 = fmaf(sg[k], w0, p0);
            w1 = fmaf(sg[k], w1, p1);
            w2 = fmaf(sg[k], w2, p2);
            w3 = fmaf(sg[k], w3, p3);
            w4 = fmaf(sg[k], w4, p4);
            w5 = fmaf(sg[k], w5, p5);
            w6 = fmaf(sg[k], w6, p6);
            w7 = fmaf(sg[k], w7, p7);
        }
        // register stage: bit 8 -> pairs (i, i+4)
        {
            float a, b;
            a = w0; b = w4; w0 = a + b; w4 = a - b;
            a = w1; b = w5; w1 = a + b; w5 = a - b;
            a = w2; b = w6; w2 = a + b; w6 = a - b;
            a = w3; b = w7; w3 = a + b; w7 = a - b;
        }

        // scaled store: two float4s per lane
        const size_t obase = (size_t)row * 512 + 4 * lane;
        float4 o0 = make_float4(S * w0, S * w1, S * w2, S * w3);
        float4 o1 = make_float4(S * w4, S * w5, S * w6, S * w7);
        *reinterpret_cast<float4*>(y + obase) = o0;
        *reinterpret_cast<float4*>(y + obase + 256) = o1;
    }
}

extern "C" void kernel_launch(void* const* d_in, const int* in_sizes, int n_in,
                              void* d_out, int out_size, void* d_ws, size_t ws_size,
                              hipStream_t stream) {
    const float* x = (const float*)d_in[0];
    const float* T = (const float*)d_in[1];
    float* y = (float*)d_out;

    const int nrows = in_sizes[0] / 256;   // 4*256*256 = 262144 rows
    const int block = 256;                  // 4 waves per block
    const int grid  = 2048;                 // 8192 waves, grid-stride over rows

    hipLaunchKernelGGL(wht512_kernel, dim3(grid), dim3(block), 0, stream,
                       x, T, y, nrows);
}

// Round 2
// 172.285 us; speedup vs baseline: 1.3244x; 1.3244x over previous
//
#include <hip/hip_runtime.h>
#include <math.h>

// WHT_expansion: rows of 256 f32 -> pad to 512 -> WHT512 -> pointwise -> WHT512 -> 512 f32.
// One row per wave64. WHT = product of 9 commuting bit-butterflies; we permute
// which bits live in registers vs lanes to minimize DS-pipe traffic:
//   xor1/xor2  -> DPP quad_perm (VALU)
//   xor16/xor32-> permlane16_swap/permlane32_swap bit-exchange (VALU) + register add/sub
//   xor4/xor8  -> ds_swizzle (only 24 DS ops per row, was 72 shfl_xor)
// First transform uses H512[x;0] = [H256 x; H256 x] (pad halves duplicate).

#define QP_XOR1  0xB1     // quad_perm [1,0,3,2]
#define QP_XOR2  0x4E     // quad_perm [2,3,0,1]
#define SWZ_XOR4 0x101F   // ds_swizzle BitMode xor=4, and=0x1F
#define SWZ_XOR8 0x201F   // ds_swizzle BitMode xor=8, and=0x1F

#define DPP_P(v, CTRL) __int_as_float(__builtin_amdgcn_update_dpp( \
    0, __float_as_int(v), CTRL, 0xf, 0xf, false))
#define SWZ_P(v, PAT) __int_as_float(__builtin_amdgcn_ds_swizzle( \
    __float_as_int(v), PAT))
#define BTF(a, b) { float _t = (a); (a) = _t + (b); (b) = _t - (b); }

__device__ __forceinline__ void pl32_swap(float &a, float &b) {
    auto r = __builtin_amdgcn_permlane32_swap(
        (int)__float_as_uint(a), (int)__float_as_uint(b), false, false);
    a = __uint_as_float((unsigned)r[0]);
    b = __uint_as_float((unsigned)r[1]);
}
__device__ __forceinline__ void pl16_swap(float &a, float &b) {
    auto r = __builtin_amdgcn_permlane16_swap(
        (int)__float_as_uint(a), (int)__float_as_uint(b), false, false);
    a = __uint_as_float((unsigned)r[0]);
    b = __uint_as_float((unsigned)r[1]);
}

__global__ __launch_bounds__(256) void wht512_kernel(
    const float* __restrict__ x, const float* __restrict__ T,
    float* __restrict__ y, int nrows)
{
    const int lane = threadIdx.x & 63;
    const int wib  = threadIdx.x >> 6;
    const int wpb  = blockDim.x >> 6;
    const int wave   = blockIdx.x * wpb + wib;
    const int nwaves = gridDim.x * wpb;

    const float S = 0.044194173824159216f; // 2^-4.5 = 1/sqrt(512)

    // signs for lane-bit butterflies (bit k of lane): +1 if clear
    const float sg0 = (lane & 1) ? -1.f : 1.f;
    const float sg1 = (lane & 2) ? -1.f : 1.f;
    const float sg2 = (lane & 4) ? -1.f : 1.f;
    const float sg3 = (lane & 8) ? -1.f : 1.f;

    // |T| hoisted, in the layout present at pointwise time:
    //   element bits: b7=c0, b6=c1, b5..b2 = lane bits 3..0, b1 = lane bit 4, b0 = lane bit 5
    const int tbase = ((lane & 15) << 2) + (((lane >> 4) & 1) << 1) + ((lane >> 5) & 1);
    float Ta[8]; // index = c0 + 2*c1 + 4*h
#pragma unroll
    for (int h = 0; h < 2; ++h)
#pragma unroll
        for (int c1 = 0; c1 < 2; ++c1)
#pragma unroll
            for (int c0 = 0; c0 < 2; ++c0)
                Ta[(h << 2) | (c1 << 1) | c0] =
                    fabsf(T[h * 256 + c0 * 128 + c1 * 64 + tbase]);

    for (int row = wave; row < nrows; row += nwaves) {
        const size_t ibase = (size_t)row * 256 + 4 * lane;
        float4 xa = *reinterpret_cast<const float4*>(x + ibase);
        float v0 = xa.x, v1 = xa.y, v2 = xa.z, v3 = xa.w;
        // layout: regs c0=b0, c1=b1; lanes l0..l5 = b2..b7

        // ---- WHT-256 ----
        // reg stages b0, b1
        BTF(v0, v1); BTF(v2, v3);
        BTF(v0, v2); BTF(v1, v3);
        // lane stage b2 (xor1) via DPP
        { float p;
          p = DPP_P(v0, QP_XOR1); v0 = fmaf(sg0, v0, p);
          p = DPP_P(v1, QP_XOR1); v1 = fmaf(sg0, v1, p);
          p = DPP_P(v2, QP_XOR1); v2 = fmaf(sg0, v2, p);
          p = DPP_P(v3, QP_XOR1); v3 = fmaf(sg0, v3, p); }
        // lane stage b3 (xor2) via DPP
        { float p;
          p = DPP_P(v0, QP_XOR2); v0 = fmaf(sg1, v0, p);
          p = DPP_P(v1, QP_XOR2); v1 = fmaf(sg1, v1, p);
          p = DPP_P(v2, QP_XOR2); v2 = fmaf(sg1, v2, p);
          p = DPP_P(v3, QP_XOR2); v3 = fmaf(sg1, v3, p); }
        // exchange reg bit c0 <-> lane bit 5 (b7), c1 <-> lane bit 4 (b6)
        pl32_swap(v0, v1); pl32_swap(v2, v3);
        pl16_swap(v0, v2); pl16_swap(v1, v3);
        // now regs: c0=b7, c1=b6; lanes: l4=b1(done), l5=b0(done)
        // reg stages b7, b6
        BTF(v0, v1); BTF(v2, v3);
        BTF(v0, v2); BTF(v1, v3);
        // lane stage b4 (xor4), b5 (xor8) via ds_swizzle
        { float p;
          p = SWZ_P(v0, SWZ_XOR4); v0 = fmaf(sg2, v0, p);
          p = SWZ_P(v1, SWZ_XOR4); v1 = fmaf(sg2, v1, p);
          p = SWZ_P(v2, SWZ_XOR4); v2 = fmaf(sg2, v2, p);
          p = SWZ_P(v3, SWZ_XOR4); v3 = fmaf(sg2, v3, p); }
        { float p;
          p = SWZ_P(v0, SWZ_XOR8); v0 = fmaf(sg3, v0, p);
          p = SWZ_P(v1, SWZ_XOR8); v1 = fmaf(sg3, v1, p);
          p = SWZ_P(v2, SWZ_XOR8); v2 = fmaf(sg3, v2, p);
          p = SWZ_P(v3, SWZ_XOR8); v3 = fmaf(sg3, v3, p); }

        // f1 = S*h duplicated into both halves; pointwise nonlinearity
        const float u0 = S * v0, u1 = S * v1, u2 = S * v2, u3 = S * v3;
        const float th0 = tanhf(u0), th1 = tanhf(u1), th2 = tanhf(u2), th3 = tanhf(u3);
        const float ab0 = fabsf(u0), ab1 = fabsf(u1), ab2 = fabsf(u2), ab3 = fabsf(u3);

        float w0 = th0 * fmaxf(ab0 - Ta[0], 0.f);
        float w1 = th1 * fmaxf(ab1 - Ta[1], 0.f);
        float w2 = th2 * fmaxf(ab2 - Ta[2], 0.f);
        float w3 = th3 * fmaxf(ab3 - Ta[3], 0.f);
        float w4 = th0 * fmaxf(ab0 - Ta[4], 0.f);
        float w5 = th1 * fmaxf(ab1 - Ta[5], 0.f);
        float w6 = th2 * fmaxf(ab2 - Ta[6], 0.f);
        float w7 = th3 * fmaxf(ab3 - Ta[7], 0.f);
        // f3[0] = f1[0]: element j=0,h=0 sits at lane 0, reg 0
        w0 = (lane == 0) ? u0 : w0;

        // ---- WHT-512 ----
        // regs: c0=b7, c1=b6, c2=b8; lanes: l0..l3=b2..b5, l4=b1, l5=b0
        // reg stages b7, b6, b8
        BTF(w0, w1); BTF(w2, w3); BTF(w4, w5); BTF(w6, w7);
        BTF(w0, w2); BTF(w1, w3); BTF(w4, w6); BTF(w5, w7);
        BTF(w0, w4); BTF(w1, w5); BTF(w2, w6); BTF(w3, w7);
        // exchange c0 <-> l5 (b0), c1 <-> l4 (b1)
        pl32_swap(w0, w1); pl32_swap(w2, w3); pl32_swap(w4, w5); pl32_swap(w6, w7);
        pl16_swap(w0, w2); pl16_swap(w1, w3); pl16_swap(w4, w6); pl16_swap(w5, w7);
        // now regs: c0=b0, c1=b1, c2=b8; lanes l4=b6(done), l5=b7(done)
        // reg stages b0, b1
        BTF(w0, w1); BTF(w2, w3); BTF(w4, w5); BTF(w6, w7);
        BTF(w0, w2); BTF(w1, w3); BTF(w4, w6); BTF(w5, w7);
        // lane stage b2 (xor1) via DPP
        { float p;
          p = DPP_P(w0, QP_XOR1); w0 = fmaf(sg0, w0, p);
          p = DPP_P(w1, QP_XOR1); w1 = fmaf(sg0, w1, p);
          p = DPP_P(w2, QP_XOR1); w2 = fmaf(sg0, w2, p);
          p = DPP_P(w3, QP_XOR1); w3 = fmaf(sg0, w3, p);
          p = DPP_P(w4, QP_XOR1); w4 = fmaf(sg0, w4, p);
          p = DPP_P(w5, QP_XOR1); w5 = fmaf(sg0, w5, p);
          p = DPP_P(w6, QP_XOR1); w6 = fmaf(sg0, w6, p);
          p = DPP_P(w7, QP_XOR1); w7 = fmaf(sg0, w7, p); }
        // lane stage b3 (xor2) via DPP
        { float p;
          p = DPP_P(w0, QP_XOR2); w0 = fmaf(sg1, w0, p);
          p = DPP_P(w1, QP_XOR2); w1 = fmaf(sg1, w1, p);
          p = DPP_P(w2, QP_XOR2); w2 = fmaf(sg1, w2, p);
          p = DPP_P(w3, QP_XOR2); w3 = fmaf(sg1, w3, p);
          p = DPP_P(w4, QP_XOR2); w4 = fmaf(sg1, w4, p);
          p = DPP_P(w5, QP_XOR2); w5 = fmaf(sg1, w5, p);
          p = DPP_P(w6, QP_XOR2); w6 = fmaf(sg1, w6, p);
          p = DPP_P(w7, QP_XOR2); w7 = fmaf(sg1, w7, p); }
        // lane stage b4 (xor4) via ds_swizzle
        { float p;
          p = SWZ_P(w0, SWZ_XOR4); w0 = fmaf(sg2, w0, p);
          p = SWZ_P(w1, SWZ_XOR4); w1 = fmaf(sg2, w1, p);
          p = SWZ_P(w2, SWZ_XOR4); w2 = fmaf(sg2, w2, p);
          p = SWZ_P(w3, SWZ_XOR4); w3 = fmaf(sg2, w3, p);
          p = SWZ_P(w4, SWZ_XOR4); w4 = fmaf(sg2, w4, p);
          p = SWZ_P(w5, SWZ_XOR4); w5 = fmaf(sg2, w5, p);
          p = SWZ_P(w6, SWZ_XOR4); w6 = fmaf(sg2, w6, p);
          p = SWZ_P(w7, SWZ_XOR4); w7 = fmaf(sg2, w7, p); }
        // lane stage b5 (xor8) via ds_swizzle
        { float p;
          p = SWZ_P(w0, SWZ_XOR8); w0 = fmaf(sg3, w0, p);
          p = SWZ_P(w1, SWZ_XOR8); w1 = fmaf(sg3, w1, p);
          p = SWZ_P(w2, SWZ_XOR8); w2 = fmaf(sg3, w2, p);
          p = SWZ_P(w3, SWZ_XOR8); w3 = fmaf(sg3, w3, p);
          p = SWZ_P(w4, SWZ_XOR8); w4 = fmaf(sg3, w4, p);
          p = SWZ_P(w5, SWZ_XOR8); w5 = fmaf(sg3, w5, p);
          p = SWZ_P(w6, SWZ_XOR8); w6 = fmaf(sg3, w6, p);
          p = SWZ_P(w7, SWZ_XOR8); w7 = fmaf(sg3, w7, p); }

        // final layout: i = c2*256 + lane*4 + (c1*2 + c0); reg order == quad order
        const size_t obase = (size_t)row * 512 + 4 * lane;
        *reinterpret_cast<float4*>(y + obase) =
            make_float4(S * w0, S * w1, S * w2, S * w3);
        *reinterpret_cast<float4*>(y + obase + 256) =
            make_float4(S * w4, S * w5, S * w6, S * w7);
    }
}

extern "C" void kernel_launch(void* const* d_in, const int* in_sizes, int n_in,
                              void* d_out, int out_size, void* d_ws, size_t ws_size,
                              hipStream_t stream) {
    const float* x = (const float*)d_in[0];
    const float* T = (const float*)d_in[1];
    float* y = (float*)d_out;

    const int nrows = in_sizes[0] / 256;   // 262144 rows
    const int block = 256;                  // 4 waves per block
    const int grid  = 2048;                 // 8192 waves, grid-stride over rows

    hipLaunchKernelGGL(wht512_kernel, dim3(grid), dim3(block), 0, stream,
                       x, T, y, nrows);
}

// Round 3
// 140.929 us; speedup vs baseline: 1.6191x; 1.2225x over previous
//
#include <hip/hip_runtime.h>
#include <math.h>

// WHT_expansion: rows of 256 f32 -> pad to 512 -> WHT512 -> pointwise -> WHT512 -> 512 f32.
// One row per wave64. WHT = product of 9 commuting bit-butterflies; bits are
// assigned to registers/lanes to minimize DS-pipe traffic:
//   lane xor1/xor2 -> DPP quad_perm (VALU)
//   lane xor8      -> DPP row_ror:8 (VALU; (i+8)&15 == i^8 within 16-lane rows)
//   lane xor16/32  -> permlane16/32_swap bit-exchange (VALU) + register add/sub
//   lane xor4      -> ds_swizzle (the only exchange with no VALU path): 12 DS/row
// First transform uses H512[x;0] = [H256 x; H256 x] (pad halves duplicate).
// tanh via branchless exp2/rcp (error ~1e-6 << 8.4e-2 threshold), f1-scale S
// folded into the exp2 constant and the threshold fma.

#define QP_XOR1  0xB1     // quad_perm [1,0,3,2]
#define QP_XOR2  0x4E     // quad_perm [2,3,0,1]
#define ROR8     0x128    // row_ror:8  (16-lane rows; == xor8)
#define SWZ_XOR4 0x101F   // ds_swizzle BitMode xor=4, and=0x1F

#define DPP_P(v, CTRL) __int_as_float(__builtin_amdgcn_update_dpp( \
    0, __float_as_int(v), CTRL, 0xf, 0xf, false))
#define SWZ_P(v, PAT) __int_as_float(__builtin_amdgcn_ds_swizzle( \
    __float_as_int(v), PAT))
#define BTF(a, b) { float _t = (a); (a) = _t + (b); (b) = _t - (b); }

typedef float f32x4 __attribute__((ext_vector_type(4)));

__device__ __forceinline__ void pl32_swap(float &a, float &b) {
    auto r = __builtin_amdgcn_permlane32_swap(
        (int)__float_as_uint(a), (int)__float_as_uint(b), false, false);
    a = __uint_as_float((unsigned)r[0]);
    b = __uint_as_float((unsigned)r[1]);
}
__device__ __forceinline__ void pl16_swap(float &a, float &b) {
    auto r = __builtin_amdgcn_permlane16_swap(
        (int)__float_as_uint(a), (int)__float_as_uint(b), false, false);
    a = __uint_as_float((unsigned)r[0]);
    b = __uint_as_float((unsigned)r[1]);
}

__global__ __launch_bounds__(256) void wht512_kernel(
    const float* __restrict__ x, const float* __restrict__ T,
    float* __restrict__ y, int nrows)
{
    const int lane = threadIdx.x & 63;
    const int wib  = threadIdx.x >> 6;
    const int wpb  = blockDim.x >> 6;
    const int wave   = blockIdx.x * wpb + wib;
    const int nwaves = gridDim.x * wpb;

    const float S = 0.044194173824159216f;   // 2^-4.5 = 1/sqrt(512)
    const float K = -2.885390081777927f * S; // -2*log2(e)*S, folds S into tanh arg

    // signs for lane-bit butterflies: +1 if lane bit clear
    const float sg0 = (lane & 1) ? -1.f : 1.f;
    const float sg1 = (lane & 2) ? -1.f : 1.f;
    const float sg2 = (lane & 4) ? -1.f : 1.f;
    const float sg3 = (lane & 8) ? -1.f : 1.f;

    // |T| hoisted, in the layout present at pointwise time:
    //   element bits: b7=c0, b6=c1, b5..b2 = lane bits 3..0, b1 = lane bit 4, b0 = lane bit 5
    const int tbase = ((lane & 15) << 2) + (((lane >> 4) & 1) << 1) + ((lane >> 5) & 1);
    float Ta[8]; // index = c0 + 2*c1 + 4*h
#pragma unroll
    for (int h = 0; h < 2; ++h)
#pragma unroll
        for (int c1 = 0; c1 < 2; ++c1)
#pragma unroll
            for (int c0 = 0; c0 < 2; ++c0)
                Ta[(h << 2) | (c1 << 1) | c0] =
                    fabsf(T[h * 256 + c0 * 128 + c1 * 64 + tbase]);

    for (int row = wave; row < nrows; row += nwaves) {
        const size_t ibase = (size_t)row * 256 + 4 * lane;
        float4 xa = *reinterpret_cast<const float4*>(x + ibase);
        float v0 = xa.x, v1 = xa.y, v2 = xa.z, v3 = xa.w;
        // layout: regs c0=b0, c1=b1; lanes l0..l5 = b2..b7

        // ---- WHT-256 ----
        // reg stages b0, b1
        BTF(v0, v1); BTF(v2, v3);
        BTF(v0, v2); BTF(v1, v3);
        // lane stage b2 (xor1) via DPP quad_perm
        { float p;
          p = DPP_P(v0, QP_XOR1); v0 = fmaf(sg0, v0, p);
          p = DPP_P(v1, QP_XOR1); v1 = fmaf(sg0, v1, p);
          p = DPP_P(v2, QP_XOR1); v2 = fmaf(sg0, v2, p);
          p = DPP_P(v3, QP_XOR1); v3 = fmaf(sg0, v3, p); }
        // lane stage b3 (xor2) via DPP quad_perm
        { float p;
          p = DPP_P(v0, QP_XOR2); v0 = fmaf(sg1, v0, p);
          p = DPP_P(v1, QP_XOR2); v1 = fmaf(sg1, v1, p);
          p = DPP_P(v2, QP_XOR2); v2 = fmaf(sg1, v2, p);
          p = DPP_P(v3, QP_XOR2); v3 = fmaf(sg1, v3, p); }
        // lane stage b5 (xor8) via DPP row_ror:8
        { float p;
          p = DPP_P(v0, ROR8); v0 = fmaf(sg3, v0, p);
          p = DPP_P(v1, ROR8); v1 = fmaf(sg3, v1, p);
          p = DPP_P(v2, ROR8); v2 = fmaf(sg3, v2, p);
          p = DPP_P(v3, ROR8); v3 = fmaf(sg3, v3, p); }
        // lane stage b4 (xor4) via ds_swizzle
        { float p;
          p = SWZ_P(v0, SWZ_XOR4); v0 = fmaf(sg2, v0, p);
          p = SWZ_P(v1, SWZ_XOR4); v1 = fmaf(sg2, v1, p);
          p = SWZ_P(v2, SWZ_XOR4); v2 = fmaf(sg2, v2, p);
          p = SWZ_P(v3, SWZ_XOR4); v3 = fmaf(sg2, v3, p); }
        // exchange reg bit c0 <-> lane bit 5 (b7), c1 <-> lane bit 4 (b6)
        pl32_swap(v0, v1); pl32_swap(v2, v3);
        pl16_swap(v0, v2); pl16_swap(v1, v3);
        // now regs: c0=b7, c1=b6; lanes: l4=b1(done), l5=b0(done)
        // reg stages b7, b6
        BTF(v0, v1); BTF(v2, v3);
        BTF(v0, v2); BTF(v1, v3);

        // ---- pointwise: f1 = S*h (duplicated halves) ----
        // th = tanh(S*h) via exp2/rcp with S folded into K; r = max(S*|h| - Ta, 0)
        const float ab0 = fabsf(v0), ab1 = fabsf(v1), ab2 = fabsf(v2), ab3 = fabsf(v3);
        float t, th0, th1, th2, th3;
        t = __builtin_amdgcn_exp2f(K * ab0);
        th0 = copysignf((1.f - t) * __builtin_amdgcn_rcpf(1.f + t), v0);
        t = __builtin_amdgcn_exp2f(K * ab1);
        th1 = copysignf((1.f - t) * __builtin_amdgcn_rcpf(1.f + t), v1);
        t = __builtin_amdgcn_exp2f(K * ab2);
        th2 = copysignf((1.f - t) * __builtin_amdgcn_rcpf(1.f + t), v2);
        t = __builtin_amdgcn_exp2f(K * ab3);
        th3 = copysignf((1.f - t) * __builtin_amdgcn_rcpf(1.f + t), v3);

        float w0 = th0 * fmaxf(fmaf(S, ab0, -Ta[0]), 0.f);
        float w1 = th1 * fmaxf(fmaf(S, ab1, -Ta[1]), 0.f);
        float w2 = th2 * fmaxf(fmaf(S, ab2, -Ta[2]), 0.f);
        float w3 = th3 * fmaxf(fmaf(S, ab3, -Ta[3]), 0.f);
        float w4 = th0 * fmaxf(fmaf(S, ab0, -Ta[4]), 0.f);
        float w5 = th1 * fmaxf(fmaf(S, ab1, -Ta[5]), 0.f);
        float w6 = th2 * fmaxf(fmaf(S, ab2, -Ta[6]), 0.f);
        float w7 = th3 * fmaxf(fmaf(S, ab3, -Ta[7]), 0.f);
        // f3[0] = f1[0]: element j=0,h=0 sits at lane 0, reg 0
        w0 = (lane == 0) ? S * v0 : w0;

        // ---- WHT-512 ----
        // regs: c0=b7, c1=b6, c2=b8; lanes: l0..l3=b2..b5, l4=b1, l5=b0
        // reg stages b7, b6, b8
        BTF(w0, w1); BTF(w2, w3); BTF(w4, w5); BTF(w6, w7);
        BTF(w0, w2); BTF(w1, w3); BTF(w4, w6); BTF(w5, w7);
        BTF(w0, w4); BTF(w1, w5); BTF(w2, w6); BTF(w3, w7);
        // exchange c0 <-> l5 (b0), c1 <-> l4 (b1)
        pl32_swap(w0, w1); pl32_swap(w2, w3); pl32_swap(w4, w5); pl32_swap(w6, w7);
        pl16_swap(w0, w2); pl16_swap(w1, w3); pl16_swap(w4, w6); pl16_swap(w5, w7);
        // now regs: c0=b0, c1=b1, c2=b8; lanes l4=b6(done), l5=b7(done)
        // reg stages b0, b1
        BTF(w0, w1); BTF(w2, w3); BTF(w4, w5); BTF(w6, w7);
        BTF(w0, w2); BTF(w1, w3); BTF(w4, w6); BTF(w5, w7);
        // lane stage b2 (xor1) via DPP quad_perm
        { float p;
          p = DPP_P(w0, QP_XOR1); w0 = fmaf(sg0, w0, p);
          p = DPP_P(w1, QP_XOR1); w1 = fmaf(sg0, w1, p);
          p = DPP_P(w2, QP_XOR1); w2 = fmaf(sg0, w2, p);
          p = DPP_P(w3, QP_XOR1); w3 = fmaf(sg0, w3, p);
          p = DPP_P(w4, QP_XOR1); w4 = fmaf(sg0, w4, p);
          p = DPP_P(w5, QP_XOR1); w5 = fmaf(sg0, w5, p);
          p = DPP_P(w6, QP_XOR1); w6 = fmaf(sg0, w6, p);
          p = DPP_P(w7, QP_XOR1); w7 = fmaf(sg0, w7, p); }
        // lane stage b3 (xor2) via DPP quad_perm
        { float p;
          p = DPP_P(w0, QP_XOR2); w0 = fmaf(sg1, w0, p);
          p = DPP_P(w1, QP_XOR2); w1 = fmaf(sg1, w1, p);
          p = DPP_P(w2, QP_XOR2); w2 = fmaf(sg1, w2, p);
          p = DPP_P(w3, QP_XOR2); w3 = fmaf(sg1, w3, p);
          p = DPP_P(w4, QP_XOR2); w4 = fmaf(sg1, w4, p);
          p = DPP_P(w5, QP_XOR2); w5 = fmaf(sg1, w5, p);
          p = DPP_P(w6, QP_XOR2); w6 = fmaf(sg1, w6, p);
          p = DPP_P(w7, QP_XOR2); w7 = fmaf(sg1, w7, p); }
        // lane stage b5 (xor8) via DPP row_ror:8
        { float p;
          p = DPP_P(w0, ROR8); w0 = fmaf(sg3, w0, p);
          p = DPP_P(w1, ROR8); w1 = fmaf(sg3, w1, p);
          p = DPP_P(w2, ROR8); w2 = fmaf(sg3, w2, p);
          p = DPP_P(w3, ROR8); w3 = fmaf(sg3, w3, p);
          p = DPP_P(w4, ROR8); w4 = fmaf(sg3, w4, p);
          p = DPP_P(w5, ROR8); w5 = fmaf(sg3, w5, p);
          p = DPP_P(w6, ROR8); w6 = fmaf(sg3, w6, p);
          p = DPP_P(w7, ROR8); w7 = fmaf(sg3, w7, p); }
        // lane stage b4 (xor4) via ds_swizzle
        { float p;
          p = SWZ_P(w0, SWZ_XOR4); w0 = fmaf(sg2, w0, p);
          p = SWZ_P(w1, SWZ_XOR4); w1 = fmaf(sg2, w1, p);
          p = SWZ_P(w2, SWZ_XOR4); w2 = fmaf(sg2, w2, p);
          p = SWZ_P(w3, SWZ_XOR4); w3 = fmaf(sg2, w3, p);
          p = SWZ_P(w4, SWZ_XOR4); w4 = fmaf(sg2, w4, p);
          p = SWZ_P(w5, SWZ_XOR4); w5 = fmaf(sg2, w5, p);
          p = SWZ_P(w6, SWZ_XOR4); w6 = fmaf(sg2, w6, p);
          p = SWZ_P(w7, SWZ_XOR4); w7 = fmaf(sg2, w7, p); }

        // final layout: i = c2*256 + lane*4 + (c1*2 + c0); reg order == quad order
        const size_t obase = (size_t)row * 512 + 4 * lane;
        f32x4 o0 = {S * w0, S * w1, S * w2, S * w3};
        f32x4 o1 = {S * w4, S * w5, S * w6, S * w7};
        __builtin_nontemporal_store(o0, reinterpret_cast<f32x4*>(y + obase));
        __builtin_nontemporal_store(o1, reinterpret_cast<f32x4*>(y + obase + 256));
    }
}

extern "C" void kernel_launch(void* const* d_in, const int* in_sizes, int n_in,
                              void* d_out, int out_size, void* d_ws, size_t ws_size,
                              hipStream_t stream) {
    const float* x = (const float*)d_in[0];
    const float* T = (const float*)d_in[1];
    float* y = (float*)d_out;

    const int nrows = in_sizes[0] / 256;   // 262144 rows
    const int block = 256;                  // 4 waves per block
    const int grid  = 2048;                 // 8192 waves, grid-stride over rows

    hipLaunchKernelGGL(wht512_kernel, dim3(grid), dim3(block), 0, stream,
                       x, T, y, nrows);
}

// Round 4
// 137.427 us; speedup vs baseline: 1.6603x; 1.0255x over previous
//
#include <hip/hip_runtime.h>
#include <math.h>

// WHT_expansion: rows of 256 f32 -> pad to 512 -> WHT512 -> pointwise -> WHT512 -> 512 f32.
// One row per wave64; TWO rows per loop iteration (loads issued back-to-back for MLP).
// WHT = product of 9 commuting bit-butterflies; bits assigned to registers/lanes
// to minimize DS-pipe traffic:
//   lane xor1/xor2 -> DPP quad_perm (VALU)
//   lane xor8      -> DPP row_ror:8 (VALU; (i+8)&15 == i^8 within 16-lane rows)
//   lane xor16/32  -> permlane16/32_swap bit-exchange (VALU) + register add/sub
//   lane xor4      -> ds_swizzle (only exchange with no VALU path): 12 DS/row
// First transform uses H512[x;0] = [H256 x; H256 x] (pad halves duplicate).
// tanh via branchless exp2/rcp (err ~1e-6), f1-scale S folded into exp2 const
// and threshold fma. NT stores for write-once output.

#define QP_XOR1  0xB1     // quad_perm [1,0,3,2]
#define QP_XOR2  0x4E     // quad_perm [2,3,0,1]
#define ROR8     0x128    // row_ror:8  (16-lane rows; == xor8)
#define SWZ_XOR4 0x101F   // ds_swizzle BitMode xor=4, and=0x1F

#define DPP_P(v, CTRL) __int_as_float(__builtin_amdgcn_update_dpp( \
    0, __float_as_int(v), CTRL, 0xf, 0xf, false))
#define SWZ_P(v, PAT) __int_as_float(__builtin_amdgcn_ds_swizzle( \
    __float_as_int(v), PAT))
#define BTF(a, b) { float _t = (a); (a) = _t + (b); (b) = _t - (b); }

typedef float f32x4 __attribute__((ext_vector_type(4)));

__device__ __forceinline__ void pl32_swap(float &a, float &b) {
    auto r = __builtin_amdgcn_permlane32_swap(
        (int)__float_as_uint(a), (int)__float_as_uint(b), false, false);
    a = __uint_as_float((unsigned)r[0]);
    b = __uint_as_float((unsigned)r[1]);
}
__device__ __forceinline__ void pl16_swap(float &a, float &b) {
    auto r = __builtin_amdgcn_permlane16_swap(
        (int)__float_as_uint(a), (int)__float_as_uint(b), false, false);
    a = __uint_as_float((unsigned)r[0]);
    b = __uint_as_float((unsigned)r[1]);
}

__global__ __launch_bounds__(256) void wht512_kernel(
    const float* __restrict__ x, const float* __restrict__ T,
    float* __restrict__ y, int nrows)
{
    const int lane = threadIdx.x & 63;
    const int wib  = threadIdx.x >> 6;
    const int wpb  = blockDim.x >> 6;
    const int wave   = blockIdx.x * wpb + wib;
    const int nwaves = gridDim.x * wpb;

    const float S = 0.044194173824159216f;   // 2^-4.5 = 1/sqrt(512)
    const float K = -2.885390081777927f * S; // -2*log2(e)*S, folds S into tanh arg

    // signs for lane-bit butterflies: +1 if lane bit clear
    const float sg0 = (lane & 1) ? -1.f : 1.f;
    const float sg1 = (lane & 2) ? -1.f : 1.f;
    const float sg2 = (lane & 4) ? -1.f : 1.f;
    const float sg3 = (lane & 8) ? -1.f : 1.f;

    // |T| hoisted, in the layout present at pointwise time:
    //   element bits: b7=c0, b6=c1, b5..b2 = lane bits 3..0, b1 = lane bit 4, b0 = lane bit 5
    const int tbase = ((lane & 15) << 2) + (((lane >> 4) & 1) << 1) + ((lane >> 5) & 1);
    float Ta[8]; // index = c0 + 2*c1 + 4*h
#pragma unroll
    for (int h = 0; h < 2; ++h)
#pragma unroll
        for (int c1 = 0; c1 < 2; ++c1)
#pragma unroll
            for (int c0 = 0; c0 < 2; ++c0)
                Ta[(h << 2) | (c1 << 1) | c0] =
                    fabsf(T[h * 256 + c0 * 128 + c1 * 64 + tbase]);

    auto do_row = [&](float v0, float v1, float v2, float v3,
                      f32x4 &o0, f32x4 &o1) {
        // layout: regs c0=b0, c1=b1; lanes l0..l5 = b2..b7
        // ---- WHT-256 ----
        BTF(v0, v1); BTF(v2, v3);
        BTF(v0, v2); BTF(v1, v3);
        { float p;
          p = DPP_P(v0, QP_XOR1); v0 = fmaf(sg0, v0, p);
          p = DPP_P(v1, QP_XOR1); v1 = fmaf(sg0, v1, p);
          p = DPP_P(v2, QP_XOR1); v2 = fmaf(sg0, v2, p);
          p = DPP_P(v3, QP_XOR1); v3 = fmaf(sg0, v3, p); }
        { float p;
          p = DPP_P(v0, QP_XOR2); v0 = fmaf(sg1, v0, p);
          p = DPP_P(v1, QP_XOR2); v1 = fmaf(sg1, v1, p);
          p = DPP_P(v2, QP_XOR2); v2 = fmaf(sg1, v2, p);
          p = DPP_P(v3, QP_XOR2); v3 = fmaf(sg1, v3, p); }
        { float p;
          p = DPP_P(v0, ROR8); v0 = fmaf(sg3, v0, p);
          p = DPP_P(v1, ROR8); v1 = fmaf(sg3, v1, p);
          p = DPP_P(v2, ROR8); v2 = fmaf(sg3, v2, p);
          p = DPP_P(v3, ROR8); v3 = fmaf(sg3, v3, p); }
        { float p;
          p = SWZ_P(v0, SWZ_XOR4); v0 = fmaf(sg2, v0, p);
          p = SWZ_P(v1, SWZ_XOR4); v1 = fmaf(sg2, v1, p);
          p = SWZ_P(v2, SWZ_XOR4); v2 = fmaf(sg2, v2, p);
          p = SWZ_P(v3, SWZ_XOR4); v3 = fmaf(sg2, v3, p); }
        pl32_swap(v0, v1); pl32_swap(v2, v3);
        pl16_swap(v0, v2); pl16_swap(v1, v3);
        // regs: c0=b7, c1=b6; lanes l4=b1(done), l5=b0(done)
        BTF(v0, v1); BTF(v2, v3);
        BTF(v0, v2); BTF(v1, v3);

        // ---- pointwise ----
        const float ab0 = fabsf(v0), ab1 = fabsf(v1), ab2 = fabsf(v2), ab3 = fabsf(v3);
        float t, th0, th1, th2, th3;
        t = __builtin_amdgcn_exp2f(K * ab0);
        th0 = copysignf((1.f - t) * __builtin_amdgcn_rcpf(1.f + t), v0);
        t = __builtin_amdgcn_exp2f(K * ab1);
        th1 = copysignf((1.f - t) * __builtin_amdgcn_rcpf(1.f + t), v1);
        t = __builtin_amdgcn_exp2f(K * ab2);
        th2 = copysignf((1.f - t) * __builtin_amdgcn_rcpf(1.f + t), v2);
        t = __builtin_amdgcn_exp2f(K * ab3);
        th3 = copysignf((1.f - t) * __builtin_amdgcn_rcpf(1.f + t), v3);

        float w0 = th0 * fmaxf(fmaf(S, ab0, -Ta[0]), 0.f);
        float w1 = th1 * fmaxf(fmaf(S, ab1, -Ta[1]), 0.f);
        float w2 = th2 * fmaxf(fmaf(S, ab2, -Ta[2]), 0.f);
        float w3 = th3 * fmaxf(fmaf(S, ab3, -Ta[3]), 0.f);
        float w4 = th0 * fmaxf(fmaf(S, ab0, -Ta[4]), 0.f);
        float w5 = th1 * fmaxf(fmaf(S, ab1, -Ta[5]), 0.f);
        float w6 = th2 * fmaxf(fmaf(S, ab2, -Ta[6]), 0.f);
        float w7 = th3 * fmaxf(fmaf(S, ab3, -Ta[7]), 0.f);
        w0 = (lane == 0) ? S * v0 : w0;   // f3[0] = f1[0]

        // ---- WHT-512 ----
        // regs: c0=b7, c1=b6, c2=b8; lanes l0..l3=b2..b5, l4=b1, l5=b0
        BTF(w0, w1); BTF(w2, w3); BTF(w4, w5); BTF(w6, w7);
        BTF(w0, w2); BTF(w1, w3); BTF(w4, w6); BTF(w5, w7);
        BTF(w0, w4); BTF(w1, w5); BTF(w2, w6); BTF(w3, w7);
        pl32_swap(w0, w1); pl32_swap(w2, w3); pl32_swap(w4, w5); pl32_swap(w6, w7);
        pl16_swap(w0, w2); pl16_swap(w1, w3); pl16_swap(w4, w6); pl16_swap(w5, w7);
        // regs: c0=b0, c1=b1, c2=b8; lanes l4=b6(done), l5=b7(done)
        BTF(w0, w1); BTF(w2, w3); BTF(w4, w5); BTF(w6, w7);
        BTF(w0, w2); BTF(w1, w3); BTF(w4, w6); BTF(w5, w7);
        { float p;
          p = DPP_P(w0, QP_XOR1); w0 = fmaf(sg0, w0, p);
          p = DPP_P(w1, QP_XOR1); w1 = fmaf(sg0, w1, p);
          p = DPP_P(w2, QP_XOR1); w2 = fmaf(sg0, w2, p);
          p = DPP_P(w3, QP_XOR1); w3 = fmaf(sg0, w3, p);
          p = DPP_P(w4, QP_XOR1); w4 = fmaf(sg0, w4, p);
          p = DPP_P(w5, QP_XOR1); w5 = fmaf(sg0, w5, p);
          p = DPP_P(w6, QP_XOR1); w6 = fmaf(sg0, w6, p);
          p = DPP_P(w7, QP_XOR1); w7 = fmaf(sg0, w7, p); }
        { float p;
          p = DPP_P(w0, QP_XOR2); w0 = fmaf(sg1, w0, p);
          p = DPP_P(w1, QP_XOR2); w1 = fmaf(sg1, w1, p);
          p = DPP_P(w2, QP_XOR2); w2 = fmaf(sg1, w2, p);
          p = DPP_P(w3, QP_XOR2); w3 = fmaf(sg1, w3, p);
          p = DPP_P(w4, QP_XOR2); w4 = fmaf(sg1, w4, p);
          p = DPP_P(w5, QP_XOR2); w5 = fmaf(sg1, w5, p);
          p = DPP_P(w6, QP_XOR2); w6 = fmaf(sg1, w6, p);
          p = DPP_P(w7, QP_XOR2); w7 = fmaf(sg1, w7, p); }
        { float p;
          p = DPP_P(w0, ROR8); w0 = fmaf(sg3, w0, p);
          p = DPP_P(w1, ROR8); w1 = fmaf(sg3, w1, p);
          p = DPP_P(w2, ROR8); w2 = fmaf(sg3, w2, p);
          p = DPP_P(w3, ROR8); w3 = fmaf(sg3, w3, p);
          p = DPP_P(w4, ROR8); w4 = fmaf(sg3, w4, p);
          p = DPP_P(w5, ROR8); w5 = fmaf(sg3, w5, p);
          p = DPP_P(w6, ROR8); w6 = fmaf(sg3, w6, p);
          p = DPP_P(w7, ROR8); w7 = fmaf(sg3, w7, p); }
        { float p;
          p = SWZ_P(w0, SWZ_XOR4); w0 = fmaf(sg2, w0, p);
          p = SWZ_P(w1, SWZ_XOR4); w1 = fmaf(sg2, w1, p);
          p = SWZ_P(w2, SWZ_XOR4); w2 = fmaf(sg2, w2, p);
          p = SWZ_P(w3, SWZ_XOR4); w3 = fmaf(sg2, w3, p);
          p = SWZ_P(w4, SWZ_XOR4); w4 = fmaf(sg2, w4, p);
          p = SWZ_P(w5, SWZ_XOR4); w5 = fmaf(sg2, w5, p);
          p = SWZ_P(w6, SWZ_XOR4); w6 = fmaf(sg2, w6, p);
          p = SWZ_P(w7, SWZ_XOR4); w7 = fmaf(sg2, w7, p); }

        // final layout: i = c2*256 + lane*4 + (c1*2 + c0); reg order == quad order
        o0 = (f32x4){S * w0, S * w1, S * w2, S * w3};
        o1 = (f32x4){S * w4, S * w5, S * w6, S * w7};
    };

    const int half = nrows >> 1;
    for (int r2 = wave; r2 < half; r2 += nwaves) {
        const int rowA = 2 * r2, rowB = rowA + 1;
        // issue both loads up front (2 KB in flight per wave)
        const float4 xa = *reinterpret_cast<const float4*>(x + (size_t)rowA * 256 + 4 * lane);
        const float4 xb = *reinterpret_cast<const float4*>(x + (size_t)rowB * 256 + 4 * lane);

        f32x4 a0, a1, b0, b1;
        do_row(xa.x, xa.y, xa.z, xa.w, a0, a1);
        {
            const size_t obase = (size_t)rowA * 512 + 4 * lane;
            __builtin_nontemporal_store(a0, reinterpret_cast<f32x4*>(y + obase));
            __builtin_nontemporal_store(a1, reinterpret_cast<f32x4*>(y + obase + 256));
        }
        do_row(xb.x, xb.y, xb.z, xb.w, b0, b1);
        {
            const size_t obase = (size_t)rowB * 512 + 4 * lane;
            __builtin_nontemporal_store(b0, reinterpret_cast<f32x4*>(y + obase));
            __builtin_nontemporal_store(b1, reinterpret_cast<f32x4*>(y + obase + 256));
        }
    }
}

extern "C" void kernel_launch(void* const* d_in, const int* in_sizes, int n_in,
                              void* d_out, int out_size, void* d_ws, size_t ws_size,
                              hipStream_t stream) {
    const float* x = (const float*)d_in[0];
    const float* T = (const float*)d_in[1];
    float* y = (float*)d_out;

    const int nrows = in_sizes[0] / 256;   // 262144 rows
    const int block = 256;                  // 4 waves per block
    const int grid  = 2048;                 // 8192 waves, 2 rows per wave-iter

    hipLaunchKernelGGL(wht512_kernel, dim3(grid), dim3(block), 0, stream,
                       x, T, y, nrows);
}